// Round 1
// 686.377 us; speedup vs baseline: 1.0945x; 1.0945x over previous
//
#include <hip/hip_runtime.h>
#include <stdint.h>

#define B 4
#define N 16384
#define D 512
#define H 256
#define NROWS (B * N)
#define K_SEL 11468
#define N_TOP 10322
#define N_RAND 1146
#define N_REM (N - N_TOP) /* 6062 */
#define HALF_CNT ((B * N_REM) / 2) /* 12124 */

typedef float v2f __attribute__((ext_vector_type(2)));
typedef float v4f __attribute__((ext_vector_type(4)));

// acc.(lo,hi) += (xs.lo, xs.lo) * (w.lo, w.hi)   [xs = SGPR pair]
#define PKS_LO(acc, xs, w)                                             \
  asm("v_pk_fma_f32 %0, %1, %2, %0 op_sel_hi:[0,1,1]"                  \
      : "+v"(acc)                                                      \
      : "s"(xs), "v"(w))
// acc.(lo,hi) += (xs.hi, xs.hi) * (w.lo, w.hi)
#define PKS_HI(acc, xs, w)                                             \
  asm("v_pk_fma_f32 %0, %1, %2, %0 op_sel:[1,0,0] op_sel_hi:[1,1,1]"   \
      : "+v"(acc)                                                      \
      : "s"(xs), "v"(w))

// Monotone float -> uint key (larger float => larger key). No NaNs expected.
__device__ __forceinline__ uint32_t f2key(float x) {
  uint32_t u = __float_as_uint(x);
  return u ^ ((u & 0x80000000u) ? 0xFFFFFFFFu : 0x80000000u);
}

// ---- K0: weight quads: wq[(k2*256+j)*4] = {WV[2k2][j],WU[2k2][j],WV[2k2+1][j],WU[2k2+1][j]}
__global__ __launch_bounds__(256) void wprep_kernel(
    const float* __restrict__ WV, const float* __restrict__ WU,
    float* __restrict__ wqf) {
  const int k2 = blockIdx.x;  // 0..255
  const int j = threadIdx.x;  // 0..255
  v4f p;
  p.x = WV[(2 * k2) * H + j];
  p.y = WU[(2 * k2) * H + j];
  p.z = WV[(2 * k2 + 1) * H + j];
  p.w = WU[(2 * k2 + 1) * H + j];
  *(reinterpret_cast<v4f*>(wqf) + (k2 * H + j)) = p;
}

// ---- K1: fused gated-attention raw scores. 2048 blocks x 256 thr (4 waves).
// wave = (rg = rowgroup of 16 rows, ch = col half). lane covers cols
// j1=ch*128+lane, j2=j1+64. x via s_load (SGPR), w via global dwordx4 (VGPR).
// R3: software-pipelined rolling halves. Per half-kt-step:
//   issue SMEM loads for half B(kt) + weights(kt+4) -> FMA half A(kt)
//   -> lgkmcnt(0) -> issue SMEM loads half A(kt+4) -> FMA half B(kt)
//   -> lgkmcnt(0). Every s_load batch gets ~256 cycles of FMA cover before
// its drain; weights double-buffered one full step (~512 cyc) ahead.
// k-order / activation / reduction order bit-identical to the R2 kernel
// (each acc[r][c] chain sees the same pk_fma sequence in the same order).
#define SB0 __builtin_amdgcn_sched_barrier(0)

#define SLOADQ(reg, i, kto)                                            \
  {                                                                    \
    const int soR = (kto) * 4 + (i) * 2048;                            \
    asm volatile("s_load_dwordx4 %0, %1, %2"                           \
                 : "=s"(reg)                                           \
                 : "s"(rowbase), "s"(soR));                            \
  }

#define SLOAD_A(kto)                                                   \
  SLOADQ(XA0, 0, kto) SLOADQ(XA1, 1, kto) SLOADQ(XA2, 2, kto)          \
  SLOADQ(XA3, 3, kto) SLOADQ(XA4, 4, kto) SLOADQ(XA5, 5, kto)          \
  SLOADQ(XA6, 6, kto) SLOADQ(XA7, 7, kto)

#define SLOAD_B(kto)                                                   \
  SLOADQ(XB0, 8, kto) SLOADQ(XB1, 9, kto) SLOADQ(XB2, 10, kto)         \
  SLOADQ(XB3, 11, kto) SLOADQ(XB4, 12, kto) SLOADQ(XB5, 13, kto)       \
  SLOADQ(XB6, 14, kto) SLOADQ(XB7, 15, kto)

// drain waits for the just-issued XB loads; also ties the A-half acc chains
// so the A FMAs cannot sink below the drain (IR-level dep + SB0 fences).
#define GATE_XB_ACCA()                                                 \
  asm volatile("s_waitcnt lgkmcnt(0)"                                  \
               : "+s"(XB0), "+s"(XB1), "+s"(XB2), "+s"(XB3),           \
                 "+s"(XB4), "+s"(XB5), "+s"(XB6), "+s"(XB7),           \
                 "+v"(acc[0][0]), "+v"(acc[0][1]), "+v"(acc[1][0]),    \
                 "+v"(acc[1][1]), "+v"(acc[2][0]), "+v"(acc[2][1]),    \
                 "+v"(acc[3][0]), "+v"(acc[3][1]), "+v"(acc[4][0]),    \
                 "+v"(acc[4][1]), "+v"(acc[5][0]), "+v"(acc[5][1]),    \
                 "+v"(acc[6][0]), "+v"(acc[6][1]), "+v"(acc[7][0]),    \
                 "+v"(acc[7][1]))

#define GATE_XA_ACCB()                                                 \
  asm volatile("s_waitcnt lgkmcnt(0)"                                  \
               : "+s"(XA0), "+s"(XA1), "+s"(XA2), "+s"(XA3),           \
                 "+s"(XA4), "+s"(XA5), "+s"(XA6), "+s"(XA7),           \
                 "+v"(acc[8][0]), "+v"(acc[8][1]), "+v"(acc[9][0]),    \
                 "+v"(acc[9][1]), "+v"(acc[10][0]), "+v"(acc[10][1]),  \
                 "+v"(acc[11][0]), "+v"(acc[11][1]), "+v"(acc[12][0]), \
                 "+v"(acc[12][1]), "+v"(acc[13][0]), "+v"(acc[13][1]), \
                 "+v"(acc[14][0]), "+v"(acc[14][1]), "+v"(acc[15][0]), \
                 "+v"(acc[15][1]))

#define ROWX(Xq, r)                                                    \
  {                                                                    \
    const v2f x01 = __builtin_shufflevector(Xq, Xq, 0, 1);             \
    const v2f x23 = __builtin_shufflevector(Xq, Xq, 2, 3);             \
    PKS_LO(acc[r][0], x01, wA01);                                      \
    PKS_HI(acc[r][0], x01, wA23);                                      \
    PKS_LO(acc[r][0], x23, wB01);                                      \
    PKS_HI(acc[r][0], x23, wB23);                                      \
    PKS_LO(acc[r][1], x01, wC01);                                      \
    PKS_HI(acc[r][1], x01, wC23);                                      \
    PKS_LO(acc[r][1], x23, wD01);                                      \
    PKS_HI(acc[r][1], x23, wD23);                                      \
  }

// one kt step of 4. Uses weights WC* (loaded for this kt one step earlier),
// prefetches WN* = weights(kt+4). Rolls SMEM halves as described above.
#define HALF_ITER(kt, WCA, WCB, WCC, WCD, WNA, WNB, WNC, WND)          \
  {                                                                    \
    SLOAD_B(kt);                                                       \
    {                                                                  \
      const size_t k2n = (size_t)(((kt) + 4) >> 1) * 256;              \
      WNA = w1p[k2n];                                                  \
      WNB = w1p[k2n + 256];                                            \
      WNC = w2p[k2n];                                                  \
      WND = w2p[k2n + 256];                                            \
    }                                                                  \
    SB0;                                                               \
    {                                                                  \
      const v2f wA01 = __builtin_shufflevector(WCA, WCA, 0, 1);        \
      const v2f wA23 = __builtin_shufflevector(WCA, WCA, 2, 3);        \
      const v2f wB01 = __builtin_shufflevector(WCB, WCB, 0, 1);        \
      const v2f wB23 = __builtin_shufflevector(WCB, WCB, 2, 3);        \
      const v2f wC01 = __builtin_shufflevector(WCC, WCC, 0, 1);        \
      const v2f wC23 = __builtin_shufflevector(WCC, WCC, 2, 3);        \
      const v2f wD01 = __builtin_shufflevector(WCD, WCD, 0, 1);        \
      const v2f wD23 = __builtin_shufflevector(WCD, WCD, 2, 3);        \
      ROWX(XA0, 0) ROWX(XA1, 1) ROWX(XA2, 2) ROWX(XA3, 3)              \
      ROWX(XA4, 4) ROWX(XA5, 5) ROWX(XA6, 6) ROWX(XA7, 7)              \
      SB0;                                                             \
      GATE_XB_ACCA();                                                  \
      SB0;                                                             \
      SLOAD_A((kt) + 4);                                               \
      SB0;                                                             \
      ROWX(XB0, 8) ROWX(XB1, 9) ROWX(XB2, 10) ROWX(XB3, 11)            \
      ROWX(XB4, 12) ROWX(XB5, 13) ROWX(XB6, 14) ROWX(XB7, 15)          \
      SB0;                                                             \
      GATE_XA_ACCB();                                                  \
      SB0;                                                             \
    }                                                                  \
  }

__global__ __launch_bounds__(256) void score_kernel(
    const float* __restrict__ feat, const float* __restrict__ wqf,
    const float* __restrict__ bV, const float* __restrict__ bU,
    const float* __restrict__ watt, const float* __restrict__ batt,
    float* __restrict__ raw) {
  const int tid = threadIdx.x;
  const int lane = tid & 63;
  const int wv4 = __builtin_amdgcn_readfirstlane(tid >> 6);
  const int rg = wv4 >> 1, ch = wv4 & 1;
  const int j1 = ch * 128 + lane;
  const int j2 = j1 + 64;
  const int row0 = blockIdx.x * 32 + rg * 16;
  const float* rowbase = feat + (size_t)row0 * D;  // uniform -> SGPR pair
  const v4f* w1p = reinterpret_cast<const v4f*>(wqf) + j1;
  const v4f* w2p = reinterpret_cast<const v4f*>(wqf) + j2;

  v2f acc[16][2];
#pragma unroll
  for (int r = 0; r < 16; ++r) {
    acc[r][0] = v2f{0.f, 0.f};
    acc[r][1] = v2f{0.f, 0.f};
  }

  v4f XA0, XA1, XA2, XA3, XA4, XA5, XA6, XA7;
  v4f XB0, XB1, XB2, XB3, XB4, XB5, XB6, XB7;
  v4f w0A, w0B, w0C, w0D, w1A, w1B, w1C, w1D;

  // prologue: A-half of kt=0 + weights(0)
  SLOAD_A(0);
  w0A = w1p[0];
  w0B = w1p[256];
  w0C = w2p[0];
  w0D = w2p[256];
  asm volatile("s_waitcnt lgkmcnt(0)"
               : "+s"(XA0), "+s"(XA1), "+s"(XA2), "+s"(XA3), "+s"(XA4),
                 "+s"(XA5), "+s"(XA6), "+s"(XA7));

#pragma unroll 1
  for (int kt = 0; kt < D; kt += 8) {
    HALF_ITER(kt, w0A, w0B, w0C, w0D, w1A, w1B, w1C, w1D);
    HALF_ITER((kt + 4), w1A, w1B, w1C, w1D, w0A, w0B, w0C, w0D);
  }
  // note: final half-iter prefetches weights(512)/rows@kt=512 — reads land in
  // allocated ws (raw region) / in-bounds feat rows; values unused.

  // epilogue (bit-identical structure to R2): per (r,c) lane-tree over 64
  // j-consecutive lanes, 4 slots in ascending-j order, then slot0+1+2+3+batt.
  const float bv1 = bV[j1], bu1 = bU[j1], wa1 = watt[j1];
  const float bv2 = bV[j2], bu2 = bU[j2], wa2 = watt[j2];
  __shared__ float red[32][4];
#pragma unroll
  for (int r = 0; r < 16; ++r) {
#pragma unroll
    for (int c = 0; c < 2; ++c) {
      const float bv = c ? bv2 : bv1;
      const float bu = c ? bu2 : bu1;
      const float wa = c ? wa2 : wa1;
      const float aV = tanhf(acc[r][c].x + bv);
      const float aU = 1.0f / (1.0f + expf(-(acc[r][c].y + bu)));
      float g = aV * aU * wa;
      for (int off = 32; off > 0; off >>= 1) g += __shfl_down(g, off, 64);
      if (lane == 0) red[rg * 16 + r][ch * 2 + c] = g;
    }
  }
  __syncthreads();
  if (tid < 32)
    raw[blockIdx.x * 32 + tid] =
        red[tid][0] + red[tid][1] + red[tid][2] + red[tid][3] + batt[0];
}

// ---- K2: Threefry scores + pick N_RAND smallest positions -> psel bitmap --
__device__ __forceinline__ void threefry(uint32_t x0, uint32_t x1,
                                         uint32_t& o0, uint32_t& o1) {
  const uint32_t k0 = 0u, k1 = 42u;
  const uint32_t ks[3] = {k0, k1, k0 ^ k1 ^ 0x1BD11BDAu};
  x0 += ks[0];
  x1 += ks[1];
  const int R0[4] = {13, 15, 26, 6}, R1[4] = {17, 29, 16, 24};
#pragma unroll
  for (int i = 0; i < 5; ++i) {
    const int* R = (i & 1) ? R1 : R0;
#pragma unroll
    for (int jr = 0; jr < 4; ++jr) {
      x0 += x1;
      x1 = (x1 << R[jr]) | (x1 >> (32 - R[jr]));
      x1 ^= x0;
    }
    x0 += ks[(i + 1) % 3];
    x1 += ks[(i + 2) % 3] + (uint32_t)(i + 1);
  }
  o0 = x0;
  o1 = x1;
}

__global__ __launch_bounds__(1024) void rand_select_kernel(
    int* __restrict__ psel) {
  const int b = blockIdx.x, t = threadIdx.x;
  __shared__ uint32_t skey[N_REM];
  __shared__ uint32_t hist[256];
  __shared__ uint32_t sh_prefix;
  __shared__ int sh_rk;
  __shared__ int s_ce[1024];
  for (int p = t; p < N_REM; p += 1024) {
    psel[b * N_REM + p] = 0;
    const int f = b * N_REM + p;
    uint32_t o0, o1, bits;
    if (f < HALF_CNT) {
      threefry((uint32_t)f, (uint32_t)(f + HALF_CNT), o0, o1);
      bits = o0;
    } else {
      threefry((uint32_t)(f - HALF_CNT), (uint32_t)f, o0, o1);
      bits = o1;
    }
    const float u = __uint_as_float((bits >> 9) | 0x3f800000u) - 1.0f;
    skey[p] = f2key(u);
  }
  __syncthreads();
  uint32_t prefix = 0;
  int rk = N_RAND;
  for (int pass = 3; pass >= 0; --pass) {
    const int sh = pass * 8;
    if (t < 256) hist[t] = 0;
    __syncthreads();
    for (int p = t; p < N_REM; p += 1024) {
      const uint32_t key = skey[p];
      if (pass == 3 || (key >> (sh + 8)) == (prefix >> (sh + 8)))
        atomicAdd(&hist[(key >> sh) & 255], 1u);
    }
    __syncthreads();
    if (t == 0) {
      int cum = 0, dsel = 0;
      for (int dgt = 0; dgt < 256; ++dgt) {
        const int h = (int)hist[dgt];
        if (cum + h >= rk) { dsel = dgt; break; }
        cum += h;
      }
      sh_prefix = prefix | ((uint32_t)dsel << sh);
      sh_rk = rk - cum;
    }
    __syncthreads();
    prefix = sh_prefix;
    rk = sh_rk;
    __syncthreads();
  }
  // stable mark: keys < T, plus first rk ties in ascending p order
  const int CH = 6;  // 1024*6 >= 6062
  const int p0 = t * CH;
  const int pe = (p0 + CH < N_REM) ? p0 + CH : N_REM;
  int ce = 0;
  for (int p = p0; p < pe; ++p) ce += (skey[p] == prefix);
  s_ce[t] = ce;
  __syncthreads();
  if (t == 0) {
    int run = 0;
    for (int i = 0; i < 1024; ++i) {
      const int a = s_ce[i];
      s_ce[i] = run;
      run += a;
    }
  }
  __syncthreads();
  int ge = s_ce[t];
  for (int p = p0; p < pe; ++p) {
    const uint32_t key = skey[p];
    const bool pick = (key < prefix) || (key == prefix && ge < rk);
    ge += (key == prefix);
    if (pick) psel[b * N_REM + p] = 1;
  }
}

// ---- exclusive scan over 1024 per-thread counts --------------------------
__device__ __forceinline__ int scan1024(int c, int* wred, int tid) {
  const int lane = tid & 63, w = tid >> 6;
  int v = c;
#pragma unroll
  for (int off = 1; off < 64; off <<= 1) {
    const int u = __shfl_up(v, off, 64);
    if (lane >= off) v += u;
  }
  if (lane == 63) wred[w] = v;
  __syncthreads();
  if (tid == 0) {
    int run = 0;
    for (int i = 0; i < 16; ++i) {
      const int a = wred[i];
      wred[i] = run;
      run += a;
    }
  }
  __syncthreads();
  const int res = wred[w] + v - c;
  __syncthreads();
  return res;
}

// ---- K3: fused softmax + top-k threshold + membership + compaction -------
__global__ __launch_bounds__(1024) void select_kernel(
    const float* __restrict__ raw, const int* __restrict__ psel,
    float* __restrict__ attn_out, int* __restrict__ sel_ws,
    float* __restrict__ out_selidx) {
  const int b = blockIdx.x, t = threadIdx.x;
  const int lane = t & 63, w = t >> 6;
  __shared__ float sraw[N];        // 64 KB
  __shared__ int whist[16][256];   // 16 KB
  __shared__ int ghist[256];
  __shared__ float fred[16];
  __shared__ int wred[16];
  __shared__ float shM, shS;
  __shared__ uint32_t sh_prefix;
  __shared__ int sh_rk;
  const float* r = raw + b * N;

  // 1. load + max
  float m = -3.0e38f;
  for (int i = 0; i < 16; ++i) {
    const int idx = t + i * 1024;
    const float v = r[idx];
    sraw[idx] = v;
    m = fmaxf(m, v);
  }
  for (int off = 32; off > 0; off >>= 1) m = fmaxf(m, __shfl_down(m, off, 64));
  if (lane == 0) fred[w] = m;
  __syncthreads();
  if (t == 0) {
    float mm = fred[0];
    for (int i = 1; i < 16; ++i) mm = fmaxf(mm, fred[i]);
    shM = mm;
  }
  __syncthreads();
  const float M = shM;

  // 2. sum exp
  float s = 0.f;
  for (int i = 0; i < 16; ++i) s += expf(sraw[t + i * 1024] - M);
  for (int off = 32; off > 0; off >>= 1) s += __shfl_down(s, off, 64);
  if (lane == 0) fred[w] = s;
  __syncthreads();
  if (t == 0) {
    float ss = 0.f;
    for (int i = 0; i < 16; ++i) ss += fred[i];
    shS = ss;
  }
  __syncthreads();
  const float inv = 1.0f / shS;

  // 3. attn write
  for (int i = 0; i < 16; ++i) {
    const int idx = t + i * 1024;
    attn_out[b * N + idx] = expf(sraw[idx] - M) * inv;
  }

  // 4. radix select: threshold key + stable tie count
  uint32_t prefix = 0;
  int rk = N_TOP;
  for (int pass = 3; pass >= 0; --pass) {
    const int sh = pass * 8;
#pragma unroll
    for (int q = 0; q < 4; ++q) whist[w][lane * 4 + q] = 0;
    __syncthreads();
    for (int i = 0; i < 16; ++i) {
      const uint32_t key = f2key(sraw[t + i * 1024]);
      if (pass == 3 || (key >> (sh + 8)) == (prefix >> (sh + 8)))
        atomicAdd(&whist[w][(key >> sh) & 255], 1);
    }
    __syncthreads();
    if (t < 256) {
      int tot = 0;
      for (int ww = 0; ww < 16; ++ww) tot += whist[ww][t];
      ghist[t] = tot;
    }
    __syncthreads();
    if (t == 0) {
      int cum = 0, dsel = 0;
      for (int dgt = 255; dgt >= 0; --dgt) {
        const int h = ghist[dgt];
        if (cum + h >= rk) { dsel = dgt; break; }
        cum += h;
      }
      sh_prefix = prefix | ((uint32_t)dsel << sh);
      sh_rk = rk - cum;
    }
    __syncthreads();
    prefix = sh_prefix;
    rk = sh_rk;
    __syncthreads();
  }
  const uint32_t T = prefix;
  const int tieTake = rk;

  // 5. membership + p-rank + psel lookup + selection (contiguous chunks)
  const int n0 = t * 16;
  int cgt = 0, ceq = 0;
  for (int i = 0; i < 16; ++i) {
    const uint32_t key = f2key(sraw[n0 + i]);
    cgt += (key > T);
    ceq += (key == T);
  }
  const int gbase = scan1024(cgt, wred, t);
  const int ebase = scan1024(ceq, wred, t);
  int grun = gbase, erun = ebase;
  unsigned selmask = 0;
  int csel = 0;
  for (int i = 0; i < 16; ++i) {
    const int n = n0 + i;
    const uint32_t key = f2key(sraw[n]);
    const bool gt = key > T, eq = key == T;
    const bool mem = gt || (eq && erun < tieTake);
    int sel;
    if (mem) {
      sel = 1;
    } else {
      const int members_before = grun + (erun < tieTake ? erun : tieTake);
      const int p = n - members_before;
      sel = psel[b * N_REM + p];
    }
    selmask |= (unsigned)sel << i;
    csel += sel;
    grun += gt;
    erun += eq;
  }
  int q = scan1024(csel, wred, t);
  for (int i = 0; i < 16; ++i) {
    if ((selmask >> i) & 1) {
      const int n = n0 + i;
      sel_ws[b * K_SEL + q] = n;
      out_selidx[b * K_SEL + q] = (float)n;
      ++q;
    }
  }
}

// ---- K4: gather selected feature rows ------------------------------------
__global__ __launch_bounds__(128) void gather_kernel(
    const float* __restrict__ feat, const int* __restrict__ sel_ws,
    float* __restrict__ out_sel) {
  const int qa = blockIdx.x;
  const int b = qa / K_SEL;
  const int n = sel_ws[qa];
  const float4* src =
      reinterpret_cast<const float4*>(feat + (size_t)(b * N + n) * D);
  float4* dst = reinterpret_cast<float4*>(out_sel + (size_t)qa * D);
  dst[threadIdx.x] = src[threadIdx.x];
}

extern "C" void kernel_launch(void* const* d_in, const int* in_sizes, int n_in,
                              void* d_out, int out_size, void* d_ws,
                              size_t ws_size, hipStream_t stream) {
  const float* feat = (const float*)d_in[0];
  const float* WV = (const float*)d_in[1];
  const float* bV = (const float*)d_in[2];
  const float* WU = (const float*)d_in[3];
  const float* bU = (const float*)d_in[4];
  const float* watt = (const float*)d_in[5];
  const float* batt = (const float*)d_in[6];

  float* out = (float*)d_out;
  float* out_selected = out;                      // B*K_SEL*D floats
  float* out_attn = out + (size_t)B * K_SEL * D;  // B*N floats
  float* out_selidx = out_attn + (size_t)B * N;   // B*K_SEL floats

  float* wqf = (float*)d_ws;                  // D/2*H*4 = 262144 floats
  float* raw = wqf + (size_t)(D / 2) * H * 4; // NROWS floats
  int* psel = (int*)(raw + NROWS);            // B*N_REM
  int* sel_ws = psel + B * N_REM;             // B*K_SEL

  wprep_kernel<<<D / 2, 256, 0, stream>>>(WV, WU, wqf);
  rand_select_kernel<<<B, 1024, 0, stream>>>(psel);
  score_kernel<<<NROWS / 32, 256, 0, stream>>>(feat, wqf, bV, bU, watt, batt,
                                               raw);
  select_kernel<<<B, 1024, 0, stream>>>(raw, psel, out_attn, sel_ws,
                                        out_selidx);
  gather_kernel<<<B * K_SEL, 128, 0, stream>>>(feat, sel_ws, out_selected);
}

// Round 2
// 432.534 us; speedup vs baseline: 1.7369x; 1.5869x over previous
//
#include <hip/hip_runtime.h>
#include <stdint.h>

#define B 4
#define N 16384
#define D 512
#define H 256
#define NROWS (B * N)
#define K_SEL 11468
#define N_TOP 10322
#define N_RAND 1146
#define N_REM (N - N_TOP) /* 6062 */
#define HALF_CNT ((B * N_REM) / 2) /* 12124 */

typedef float v4f __attribute__((ext_vector_type(4)));
typedef float f32x4 __attribute__((ext_vector_type(4)));
typedef _Float16 f16x8 __attribute__((ext_vector_type(8)));
typedef int i32x4 __attribute__((ext_vector_type(4)));

// Monotone float -> uint key (larger float => larger key). No NaNs expected.
__device__ __forceinline__ uint32_t f2key(float x) {
  uint32_t u = __float_as_uint(x);
  return u ^ ((u & 0x80000000u) ? 0xFFFFFFFFu : 0x80000000u);
}

// LDS slot swizzle for [row][32k] fp16 tiles read as 16B granules:
// granule g of row r lives at byte r*64 + ((g ^ swz(r))<<4).
// swz spreads the 16 rows of a frag read over 8 bank-quads (2-way = free).
#define SWZ(r) ((((r) & 3) ^ (((r) >> 2) & 3)))

// ---- K0: build W^T in fp16 hi/lo: wt[n][k], n: 0-255 = W_V cols, 256-511 = W_U.
// 64x64 LDS-tiled transpose, coalesced on both global sides.
__global__ __launch_bounds__(256) void wprep_kernel(
    const float* __restrict__ WV, const float* __restrict__ WU,
    _Float16* __restrict__ wt_h, _Float16* __restrict__ wt_l) {
  __shared__ _Float16 th[64][65];
  __shared__ _Float16 tl[64][65];
  const int kb = (blockIdx.x >> 3) * 64;
  const int nb = (blockIdx.x & 7) * 64;
  const int tx = threadIdx.x & 63;   // 64 consecutive lanes
  const int ty = threadIdx.x >> 6;   // 0..3
  const float* src = (nb < 256) ? WV : WU;
  const int nsrc = nb & 255;
#pragma unroll
  for (int i = 0; i < 16; ++i) {
    const int k = ty + i * 4;  // 0..63
    const float x = src[(size_t)(kb + k) * H + nsrc + tx];
    const _Float16 h = (_Float16)x;
    th[k][tx] = h;
    tl[k][tx] = (_Float16)(x - (float)h);
  }
  __syncthreads();
#pragma unroll
  for (int i = 0; i < 16; ++i) {
    const int n = ty + i * 4;  // local n
    wt_h[(size_t)(nb + n) * 512 + kb + tx] = th[tx][n];
    wt_l[(size_t)(nb + n) * 512 + kb + tx] = tl[tx][n];
  }
}

// ---- K1: fused gated-attention raw scores via MFMA (fp16 hi/lo split).
// 512 wg x 512 thr (8 waves). BM=128 rows, BN=512 (all cols), K-step 32.
// wave w: rg=w>>2 (row half of 64), cg=w&3 (col group). Wave tile 64x128:
// Ntiles 0-3 = V cols [cg*64, +64), Ntiles 4-7 = U cols [256+cg*64, +64)
// so V/U pairs for gating live in the same lane/reg (acc[mt][nt] vs [nt+4]).
// C = Xh@Wh + Xh@Wl + Xl@Wh accumulated fp32 (ll term ~2^-22, dropped).
// Single-buffer LDS, reg-staged: issue loads(kt+1) before compute(kt).
__global__ __launch_bounds__(512) void score_kernel(
    const float* __restrict__ feat, const _Float16* __restrict__ wt_h,
    const _Float16* __restrict__ wt_l, const float* __restrict__ bV,
    const float* __restrict__ bU, const float* __restrict__ watt,
    float* __restrict__ raw) {
  __shared__ _Float16 Ah[128 * 32];  // 8 KB  [row][k] swizzled
  __shared__ _Float16 Al[128 * 32];  // 8 KB
  __shared__ _Float16 Bh[512 * 32];  // 32 KB [n][k] swizzled
  __shared__ _Float16 Bl[512 * 32];  // 32 KB
  __shared__ float red[128][5];      // 2.5 KB cross-wave row partials

  const int tid = threadIdx.x;
  const int lane = tid & 63;
  const int lc = lane & 15;
  const int lg = lane >> 4;  // k-granule for frag reads
  const int w = __builtin_amdgcn_readfirstlane(tid >> 6);
  const int rg = w >> 2;  // 0..1
  const int cg = w & 3;   // 0..3
  const int row0 = blockIdx.x * 128;

  // ---- staging thread mapping (step-invariant) ----
  // A: thread covers row rA, 8 k at granule gA.
  const int rA = tid >> 2;        // 0..127
  const int gA = tid & 3;         // granule 0..3
  const float* aG = feat + (size_t)(row0 + rA) * D + gA * 8;
  const int aSlot = gA ^ SWZ(rA);
  // B: thread covers rows nB0+128*i (i=0..3), granule gB.
  const int nB0 = tid >> 2;  // 0..127
  const int gB = tid & 3;
  const int bSlot = gB ^ SWZ(nB0);  // swz invariant under +128
  const _Float16* bhG = wt_h + (size_t)nB0 * 512 + gB * 8;
  const _Float16* blG = wt_l + (size_t)nB0 * 512 + gB * 8;

  // ---- frag read offsets (step-invariant, in fp16 elems) ----
  int aoff[4], boff[8];
#pragma unroll
  for (int mt = 0; mt < 4; ++mt) {
    const int r = rg * 64 + mt * 16 + lc;
    aoff[mt] = r * 32 + ((lg ^ SWZ(r)) << 3);
  }
#pragma unroll
  for (int nt = 0; nt < 8; ++nt) {
    const int nbase = (nt < 4) ? cg * 64 + nt * 16 : 256 + cg * 64 + (nt - 4) * 16;
    const int n = nbase + lc;
    boff[nt] = n * 32 + ((lg ^ SWZ(n)) << 3);
  }

  f32x4 acc[4][8] = {};

  // staging registers
  f32x4 a0, a1;
  i32x4 bhR0, bhR1, bhR2, bhR3, blR0, blR1, blR2, blR3;

  // preload step 0
  a0 = *(const f32x4*)(aG);
  a1 = *(const f32x4*)(aG + 4);
  bhR0 = *(const i32x4*)(bhG);
  bhR1 = *(const i32x4*)(bhG + 65536);
  bhR2 = *(const i32x4*)(bhG + 131072);
  bhR3 = *(const i32x4*)(bhG + 196608);
  blR0 = *(const i32x4*)(blG);
  blR1 = *(const i32x4*)(blG + 65536);
  blR2 = *(const i32x4*)(blG + 131072);
  blR3 = *(const i32x4*)(blG + 196608);

#pragma unroll 1
  for (int kt = 0; kt < 16; ++kt) {
    __syncthreads();  // (a) previous step's frag reads complete
    // ---- stage: convert A, write A+B to LDS ----
    {
      f16x8 ahw, alw;
#pragma unroll
      for (int e = 0; e < 8; ++e) {
        const float x = (e < 4) ? a0[e] : a1[e - 4];
        const _Float16 h = (_Float16)x;
        ahw[e] = h;
        alw[e] = (_Float16)(x - (float)h);
      }
      const int aw = rA * 32 + (aSlot << 3);
      *(f16x8*)&Ah[aw] = ahw;
      *(f16x8*)&Al[aw] = alw;
      const int bw = nB0 * 32 + (bSlot << 3);
      *(i32x4*)&Bh[bw] = bhR0;
      *(i32x4*)&Bh[bw + 128 * 32] = bhR1;
      *(i32x4*)&Bh[bw + 256 * 32] = bhR2;
      *(i32x4*)&Bh[bw + 384 * 32] = bhR3;
      *(i32x4*)&Bl[bw] = blR0;
      *(i32x4*)&Bl[bw + 128 * 32] = blR1;
      *(i32x4*)&Bl[bw + 256 * 32] = blR2;
      *(i32x4*)&Bl[bw + 384 * 32] = blR3;
    }
    __syncthreads();  // (b) buffer ready
    // ---- issue loads for next step (consumed after next barrier (a)) ----
    if (kt < 15) {
      const int k0 = (kt + 1) * 32;
      a0 = *(const f32x4*)(aG + k0);
      a1 = *(const f32x4*)(aG + k0 + 4);
      bhR0 = *(const i32x4*)(bhG + k0);
      bhR1 = *(const i32x4*)(bhG + 65536 + k0);
      bhR2 = *(const i32x4*)(bhG + 131072 + k0);
      bhR3 = *(const i32x4*)(bhG + 196608 + k0);
      blR0 = *(const i32x4*)(blG + k0);
      blR1 = *(const i32x4*)(blG + 65536 + k0);
      blR2 = *(const i32x4*)(blG + 131072 + k0);
      blR3 = *(const i32x4*)(blG + 196608 + k0);
    }
    // ---- compute ----
    f16x8 ah[4], al[4];
#pragma unroll
    for (int mt = 0; mt < 4; ++mt) {
      ah[mt] = *(const f16x8*)&Ah[aoff[mt]];
      al[mt] = *(const f16x8*)&Al[aoff[mt]];
    }
#pragma unroll
    for (int nt = 0; nt < 8; ++nt) {
      const f16x8 bh = *(const f16x8*)&Bh[boff[nt]];
      const f16x8 bl = *(const f16x8*)&Bl[boff[nt]];
#pragma unroll
      for (int mt = 0; mt < 4; ++mt) {
        acc[mt][nt] =
            __builtin_amdgcn_mfma_f32_16x16x32_f16(ah[mt], bh, acc[mt][nt], 0, 0, 0);
        acc[mt][nt] =
            __builtin_amdgcn_mfma_f32_16x16x32_f16(ah[mt], bl, acc[mt][nt], 0, 0, 0);
        acc[mt][nt] =
            __builtin_amdgcn_mfma_f32_16x16x32_f16(al[mt], bh, acc[mt][nt], 0, 0, 0);
      }
    }
  }

  // ---- epilogue: gate + reduce over this wave's 64 j-columns ----
  // acc[mt][nt] element rr: row = rg*64+mt*16+(lane>>4)*4+rr, col = nbase+lc.
#pragma unroll
  for (int mt = 0; mt < 4; ++mt) {
    float rs[4] = {0.f, 0.f, 0.f, 0.f};
#pragma unroll
    for (int nt = 0; nt < 4; ++nt) {
      const int j = cg * 64 + nt * 16 + lc;
      const float bv = bV[j], bu = bU[j], wa = watt[j];
#pragma unroll
      for (int rr = 0; rr < 4; ++rr) {
        const float cV = acc[mt][nt][rr] + bv;
        const float cU = acc[mt][nt + 4][rr] + bu;
        const float e2 = __expf(2.0f * cV);
        const float aV = 1.0f - 2.0f / (e2 + 1.0f);  // tanh
        const float aU = 1.0f / (1.0f + __expf(-cU));  // sigmoid
        rs[rr] += aV * aU * wa;
      }
    }
#pragma unroll
    for (int rr = 0; rr < 4; ++rr) {
      float v = rs[rr];
      v += __shfl_xor(v, 1, 16);
      v += __shfl_xor(v, 2, 16);
      v += __shfl_xor(v, 4, 16);
      v += __shfl_xor(v, 8, 16);
      if (lc == 0) red[rg * 64 + mt * 16 + lg * 4 + rr][cg] = v;
    }
  }
  __syncthreads();
  if (tid < 128)
    raw[row0 + tid] = red[tid][0] + red[tid][1] + red[tid][2] + red[tid][3];
}

// ---- K2: Threefry scores + pick N_RAND smallest positions -> psel bitmap --
__device__ __forceinline__ void threefry(uint32_t x0, uint32_t x1,
                                         uint32_t& o0, uint32_t& o1) {
  const uint32_t k0 = 0u, k1 = 42u;
  const uint32_t ks[3] = {k0, k1, k0 ^ k1 ^ 0x1BD11BDAu};
  x0 += ks[0];
  x1 += ks[1];
  const int R0[4] = {13, 15, 26, 6}, R1[4] = {17, 29, 16, 24};
#pragma unroll
  for (int i = 0; i < 5; ++i) {
    const int* R = (i & 1) ? R1 : R0;
#pragma unroll
    for (int jr = 0; jr < 4; ++jr) {
      x0 += x1;
      x1 = (x1 << R[jr]) | (x1 >> (32 - R[jr]));
      x1 ^= x0;
    }
    x0 += ks[(i + 1) % 3];
    x1 += ks[(i + 2) % 3] + (uint32_t)(i + 1);
  }
  o0 = x0;
  o1 = x1;
}

__global__ __launch_bounds__(1024) void rand_select_kernel(
    int* __restrict__ psel) {
  const int b = blockIdx.x, t = threadIdx.x;
  __shared__ uint32_t skey[N_REM];
  __shared__ uint32_t hist[256];
  __shared__ uint32_t sh_prefix;
  __shared__ int sh_rk;
  __shared__ int s_ce[1024];
  for (int p = t; p < N_REM; p += 1024) {
    psel[b * N_REM + p] = 0;
    const int f = b * N_REM + p;
    uint32_t o0, o1, bits;
    if (f < HALF_CNT) {
      threefry((uint32_t)f, (uint32_t)(f + HALF_CNT), o0, o1);
      bits = o0;
    } else {
      threefry((uint32_t)(f - HALF_CNT), (uint32_t)f, o0, o1);
      bits = o1;
    }
    const float u = __uint_as_float((bits >> 9) | 0x3f800000u) - 1.0f;
    skey[p] = f2key(u);
  }
  __syncthreads();
  uint32_t prefix = 0;
  int rk = N_RAND;
  for (int pass = 3; pass >= 0; --pass) {
    const int sh = pass * 8;
    if (t < 256) hist[t] = 0;
    __syncthreads();
    for (int p = t; p < N_REM; p += 1024) {
      const uint32_t key = skey[p];
      if (pass == 3 || (key >> (sh + 8)) == (prefix >> (sh + 8)))
        atomicAdd(&hist[(key >> sh) & 255], 1u);
    }
    __syncthreads();
    if (t == 0) {
      int cum = 0, dsel = 0;
      for (int dgt = 0; dgt < 256; ++dgt) {
        const int h = (int)hist[dgt];
        if (cum + h >= rk) { dsel = dgt; break; }
        cum += h;
      }
      sh_prefix = prefix | ((uint32_t)dsel << sh);
      sh_rk = rk - cum;
    }
    __syncthreads();
    prefix = sh_prefix;
    rk = sh_rk;
    __syncthreads();
  }
  // stable mark: keys < T, plus first rk ties in ascending p order
  const int CH = 6;  // 1024*6 >= 6062
  const int p0 = t * CH;
  const int pe = (p0 + CH < N_REM) ? p0 + CH : N_REM;
  int ce = 0;
  for (int p = p0; p < pe; ++p) ce += (skey[p] == prefix);
  s_ce[t] = ce;
  __syncthreads();
  if (t == 0) {
    int run = 0;
    for (int i = 0; i < 1024; ++i) {
      const int a = s_ce[i];
      s_ce[i] = run;
      run += a;
    }
  }
  __syncthreads();
  int ge = s_ce[t];
  for (int p = p0; p < pe; ++p) {
    const uint32_t key = skey[p];
    const bool pick = (key < prefix) || (key == prefix && ge < rk);
    ge += (key == prefix);
    if (pick) psel[b * N_REM + p] = 1;
  }
}

// ---- exclusive scan over 1024 per-thread counts --------------------------
__device__ __forceinline__ int scan1024(int c, int* wred, int tid) {
  const int lane = tid & 63, w = tid >> 6;
  int v = c;
#pragma unroll
  for (int off = 1; off < 64; off <<= 1) {
    const int u = __shfl_up(v, off, 64);
    if (lane >= off) v += u;
  }
  if (lane == 63) wred[w] = v;
  __syncthreads();
  if (tid == 0) {
    int run = 0;
    for (int i = 0; i < 16; ++i) {
      const int a = wred[i];
      wred[i] = run;
      run += a;
    }
  }
  __syncthreads();
  const int res = wred[w] + v - c;
  __syncthreads();
  return res;
}

// ---- K3: fused softmax + top-k threshold + membership + compaction -------
__global__ __launch_bounds__(1024) void select_kernel(
    const float* __restrict__ raw, const int* __restrict__ psel,
    float* __restrict__ attn_out, int* __restrict__ sel_ws,
    float* __restrict__ out_selidx) {
  const int b = blockIdx.x, t = threadIdx.x;
  const int lane = t & 63, w = t >> 6;
  __shared__ float sraw[N];        // 64 KB
  __shared__ int whist[16][256];   // 16 KB
  __shared__ int ghist[256];
  __shared__ float fred[16];
  __shared__ int wred[16];
  __shared__ float shM, shS;
  __shared__ uint32_t sh_prefix;
  __shared__ int sh_rk;
  const float* r = raw + b * N;

  // 1. load + max
  float m = -3.0e38f;
  for (int i = 0; i < 16; ++i) {
    const int idx = t + i * 1024;
    const float v = r[idx];
    sraw[idx] = v;
    m = fmaxf(m, v);
  }
  for (int off = 32; off > 0; off >>= 1) m = fmaxf(m, __shfl_down(m, off, 64));
  if (lane == 0) fred[w] = m;
  __syncthreads();
  if (t == 0) {
    float mm = fred[0];
    for (int i = 1; i < 16; ++i) mm = fmaxf(mm, fred[i]);
    shM = mm;
  }
  __syncthreads();
  const float M = shM;

  // 2. sum exp
  float s = 0.f;
  for (int i = 0; i < 16; ++i) s += expf(sraw[t + i * 1024] - M);
  for (int off = 32; off > 0; off >>= 1) s += __shfl_down(s, off, 64);
  if (lane == 0) fred[w] = s;
  __syncthreads();
  if (t == 0) {
    float ss = 0.f;
    for (int i = 0; i < 16; ++i) ss += fred[i];
    shS = ss;
  }
  __syncthreads();
  const float inv = 1.0f / shS;

  // 3. attn write
  for (int i = 0; i < 16; ++i) {
    const int idx = t + i * 1024;
    attn_out[b * N + idx] = expf(sraw[idx] - M) * inv;
  }

  // 4. radix select: threshold key + stable tie count
  uint32_t prefix = 0;
  int rk = N_TOP;
  for (int pass = 3; pass >= 0; --pass) {
    const int sh = pass * 8;
#pragma unroll
    for (int q = 0; q < 4; ++q) whist[w][lane * 4 + q] = 0;
    __syncthreads();
    for (int i = 0; i < 16; ++i) {
      const uint32_t key = f2key(sraw[t + i * 1024]);
      if (pass == 3 || (key >> (sh + 8)) == (prefix >> (sh + 8)))
        atomicAdd(&whist[w][(key >> sh) & 255], 1);
    }
    __syncthreads();
    if (t < 256) {
      int tot = 0;
      for (int ww = 0; ww < 16; ++ww) tot += whist[ww][t];
      ghist[t] = tot;
    }
    __syncthreads();
    if (t == 0) {
      int cum = 0, dsel = 0;
      for (int dgt = 255; dgt >= 0; --dgt) {
        const int h = ghist[dgt];
        if (cum + h >= rk) { dsel = dgt; break; }
        cum += h;
      }
      sh_prefix = prefix | ((uint32_t)dsel << sh);
      sh_rk = rk - cum;
    }
    __syncthreads();
    prefix = sh_prefix;
    rk = sh_rk;
    __syncthreads();
  }
  const uint32_t T = prefix;
  const int tieTake = rk;

  // 5. membership + p-rank + psel lookup + selection (contiguous chunks)
  const int n0 = t * 16;
  int cgt = 0, ceq = 0;
  for (int i = 0; i < 16; ++i) {
    const uint32_t key = f2key(sraw[n0 + i]);
    cgt += (key > T);
    ceq += (key == T);
  }
  const int gbase = scan1024(cgt, wred, t);
  const int ebase = scan1024(ceq, wred, t);
  int grun = gbase, erun = ebase;
  unsigned selmask = 0;
  int csel = 0;
  for (int i = 0; i < 16; ++i) {
    const int n = n0 + i;
    const uint32_t key = f2key(sraw[n]);
    const bool gt = key > T, eq = key == T;
    const bool mem = gt || (eq && erun < tieTake);
    int sel;
    if (mem) {
      sel = 1;
    } else {
      const int members_before = grun + (erun < tieTake ? erun : tieTake);
      const int p = n - members_before;
      sel = psel[b * N_REM + p];
    }
    selmask |= (unsigned)sel << i;
    csel += sel;
    grun += gt;
    erun += eq;
  }
  int q = scan1024(csel, wred, t);
  for (int i = 0; i < 16; ++i) {
    if ((selmask >> i) & 1) {
      const int n = n0 + i;
      sel_ws[b * K_SEL + q] = n;
      out_selidx[b * K_SEL + q] = (float)n;
      ++q;
    }
  }
}

// ---- K4: gather selected feature rows ------------------------------------
__global__ __launch_bounds__(128) void gather_kernel(
    const float* __restrict__ feat, const int* __restrict__ sel_ws,
    float* __restrict__ out_sel) {
  const int qa = blockIdx.x;
  const int b = qa / K_SEL;
  const int n = sel_ws[qa];
  const float4* src =
      reinterpret_cast<const float4*>(feat + (size_t)(b * N + n) * D);
  float4* dst = reinterpret_cast<float4*>(out_sel + (size_t)qa * D);
  dst[threadIdx.x] = src[threadIdx.x];
}

extern "C" void kernel_launch(void* const* d_in, const int* in_sizes, int n_in,
                              void* d_out, int out_size, void* d_ws,
                              size_t ws_size, hipStream_t stream) {
  const float* feat = (const float*)d_in[0];
  const float* WV = (const float*)d_in[1];
  const float* bV = (const float*)d_in[2];
  const float* WU = (const float*)d_in[3];
  const float* bU = (const float*)d_in[4];
  const float* watt = (const float*)d_in[5];
  const float* batt = (const float*)d_in[6];
  (void)batt;  // softmax is shift-invariant; b_att cancels in all outputs

  float* out = (float*)d_out;
  float* out_selected = out;                      // B*K_SEL*D floats
  float* out_attn = out + (size_t)B * K_SEL * D;  // B*N floats
  float* out_selidx = out_attn + (size_t)B * N;   // B*K_SEL floats

  _Float16* wt_h = (_Float16*)d_ws;            // 512*512 fp16 = 512 KB
  _Float16* wt_l = wt_h + 512 * 512;           // 512 KB
  float* raw = (float*)(wt_l + 512 * 512);     // NROWS floats
  int* psel = (int*)(raw + NROWS);             // B*N_REM
  int* sel_ws = psel + B * N_REM;              // B*K_SEL

  wprep_kernel<<<64, 256, 0, stream>>>(WV, WU, wt_h, wt_l);
  rand_select_kernel<<<B, 1024, 0, stream>>>(psel);
  score_kernel<<<NROWS / 128, 512, 0, stream>>>(feat, wt_h, wt_l, bV, bU, watt,
                                                raw);
  select_kernel<<<B, 1024, 0, stream>>>(raw, psel, out_attn, sel_ws,
                                        out_selidx);
  gather_kernel<<<B * K_SEL, 128, 0, stream>>>(feat, sel_ws, out_selected);
}

// Round 3
// 371.434 us; speedup vs baseline: 2.0226x; 1.1645x over previous
//
#include <hip/hip_runtime.h>
#include <stdint.h>

#define B 4
#define N 16384
#define D 512
#define H 256
#define NROWS (B * N)
#define K_SEL 11468
#define N_TOP 10322
#define N_RAND 1146
#define N_REM (N - N_TOP) /* 6062 */
#define HALF_CNT ((B * N_REM) / 2) /* 12124 */

typedef float v4f __attribute__((ext_vector_type(4)));
typedef float f32x4 __attribute__((ext_vector_type(4)));
typedef _Float16 f16x8 __attribute__((ext_vector_type(8)));
typedef int i32x4 __attribute__((ext_vector_type(4)));

// Monotone float -> uint key (larger float => larger key). No NaNs expected.
__device__ __forceinline__ uint32_t f2key(float x) {
  uint32_t u = __float_as_uint(x);
  return u ^ ((u & 0x80000000u) ? 0xFFFFFFFFu : 0x80000000u);
}

// LDS slot swizzle for [row][32k] fp16 tiles read as 16B granules.
#define SWZ(r) ((((r) & 3) ^ (((r) >> 2) & 3)))

// ---- Threefry (matches jax.random.uniform(key(42)) stream) ---------------
__device__ __forceinline__ void threefry(uint32_t x0, uint32_t x1,
                                         uint32_t& o0, uint32_t& o1) {
  const uint32_t k0 = 0u, k1 = 42u;
  const uint32_t ks[3] = {k0, k1, k0 ^ k1 ^ 0x1BD11BDAu};
  x0 += ks[0];
  x1 += ks[1];
  const int R0[4] = {13, 15, 26, 6}, R1[4] = {17, 29, 16, 24};
#pragma unroll
  for (int i = 0; i < 5; ++i) {
    const int* R = (i & 1) ? R1 : R0;
#pragma unroll
    for (int jr = 0; jr < 4; ++jr) {
      x0 += x1;
      x1 = (x1 << R[jr]) | (x1 >> (32 - R[jr]));
      x1 ^= x0;
    }
    x0 += ks[(i + 1) % 3];
    x1 += ks[(i + 2) % 3] + (uint32_t)(i + 1);
  }
  o0 = x0;
  o1 = x1;
}

// ---- rand body: pick N_RAND smallest threefry scores -> psel bitmap.
// 256 threads. Bit-identical counts/threshold to the 1024-thread version.
__device__ __forceinline__ void rand_body(const int b, int* __restrict__ psel,
                                          char* smem, const int t) {
  uint32_t* skey = reinterpret_cast<uint32_t*>(smem);           // N_REM*4
  uint32_t* hist = reinterpret_cast<uint32_t*>(smem + 24248);   // 256*4
  int* wr4 = reinterpret_cast<int*>(smem + 25272);              // 4*4
  uint32_t* shp = reinterpret_cast<uint32_t*>(smem + 25288);
  int* shrk = reinterpret_cast<int*>(smem + 25292);
  const int lane = t & 63, w4 = t >> 6;  // 4 waves

  for (int p = t; p < N_REM; p += 256) {
    psel[b * N_REM + p] = 0;
    const int f = b * N_REM + p;
    uint32_t o0, o1, bits;
    if (f < HALF_CNT) {
      threefry((uint32_t)f, (uint32_t)(f + HALF_CNT), o0, o1);
      bits = o0;
    } else {
      threefry((uint32_t)(f - HALF_CNT), (uint32_t)f, o0, o1);
      bits = o1;
    }
    const float u = __uint_as_float((bits >> 9) | 0x3f800000u) - 1.0f;
    skey[p] = f2key(u);
  }
  __syncthreads();

  uint32_t prefix = 0;
  int rk = N_RAND;
  for (int pass = 3; pass >= 0; --pass) {
    const int sh = pass * 8;
    hist[t] = 0;
    __syncthreads();
    for (int p = t; p < N_REM; p += 256) {
      const uint32_t key = skey[p];
      if (pass == 3 || (key >> (sh + 8)) == (prefix >> (sh + 8)))
        atomicAdd(&hist[(key >> sh) & 255], 1u);
    }
    __syncthreads();
    // parallel ascending digit search (inclusive prefix scan over 256 bins)
    const int h = (int)hist[t];
    int v = h;
#pragma unroll
    for (int off = 1; off < 64; off <<= 1) {
      const int u2 = __shfl_up(v, off, 64);
      if (lane >= off) v += u2;
    }
    if (lane == 63) wr4[w4] = v;
    __syncthreads();
    int add = 0;
    for (int i = 0; i < w4; ++i) add += wr4[i];
    const int incl = v + add, excl = incl - h;
    if (incl >= rk && excl < rk) {
      *shp = prefix | ((uint32_t)t << sh);
      *shrk = rk - excl;
    }
    __syncthreads();
    prefix = *shp;
    rk = *shrk;
    __syncthreads();
  }

  // stable mark: keys < T, plus first rk ties in ascending p order
  const int CH = 24;  // 256*24 >= 6062
  const int p0 = t * CH;
  const int pe = (p0 + CH < N_REM) ? p0 + CH : N_REM;
  int ce = 0;
  for (int p = p0; p < pe; ++p) ce += (skey[p] == prefix);
  int v = ce;
#pragma unroll
  for (int off = 1; off < 64; off <<= 1) {
    const int u2 = __shfl_up(v, off, 64);
    if (lane >= off) v += u2;
  }
  if (lane == 63) wr4[w4] = v;
  __syncthreads();
  if (t == 0) {
    int run = 0;
    for (int i = 0; i < 4; ++i) {
      const int a = wr4[i];
      wr4[i] = run;
      run += a;
    }
  }
  __syncthreads();
  int ge = wr4[w4] + v - ce;
  for (int p = p0; p < pe; ++p) {
    const uint32_t key = skey[p];
    const bool pick = (key < prefix) || (key == prefix && ge < rk);
    ge += (key == prefix);
    if (pick) psel[b * N_REM + p] = 1;
  }
}

// ---- K0: fused prep. Blocks 0-63: W^T fp16 hi/lo transpose. Blocks 64-67:
// rand selection (independent; overlapped here so it costs ~nothing).
__global__ __launch_bounds__(256) void prep_kernel(
    const float* __restrict__ WV, const float* __restrict__ WU,
    _Float16* __restrict__ wt_h, _Float16* __restrict__ wt_l,
    int* __restrict__ psel) {
  __shared__ __align__(16) char pmem[25296];
  if (blockIdx.x >= 64) {
    rand_body(blockIdx.x - 64, psel, pmem, threadIdx.x);
    return;
  }
  _Float16(*th)[65] = reinterpret_cast<_Float16(*)[65]>(pmem);
  _Float16(*tl)[65] = reinterpret_cast<_Float16(*)[65]>(pmem + 8320);
  const int kb = (blockIdx.x >> 3) * 64;
  const int nb = (blockIdx.x & 7) * 64;
  const int tx = threadIdx.x & 63;
  const int ty = threadIdx.x >> 6;
  const float* src = (nb < 256) ? WV : WU;
  const int nsrc = nb & 255;
#pragma unroll
  for (int i = 0; i < 16; ++i) {
    const int k = ty + i * 4;
    const float x = src[(size_t)(kb + k) * H + nsrc + tx];
    const _Float16 h = (_Float16)x;
    th[k][tx] = h;
    tl[k][tx] = (_Float16)(x - (float)h);
  }
  __syncthreads();
#pragma unroll
  for (int i = 0; i < 16; ++i) {
    const int n = ty + i * 4;
    wt_h[(size_t)(nb + n) * 512 + kb + tx] = th[tx][n];
    wt_l[(size_t)(nb + n) * 512 + kb + tx] = tl[tx][n];
  }
}

// ---- K1: fused gated-attention raw scores via MFMA (fp16 hi/lo split).
// 512 wg x 512 thr. BM=128, BN=512, K-step 32. LDS = exactly 80 KB so two
// blocks co-reside per CU (160 KB pool) — cross-block overlap hides the
// per-step barriers. red[] aliases the A-tile region (dead by epilogue).
__global__ __launch_bounds__(512) void score_kernel(
    const float* __restrict__ feat, const _Float16* __restrict__ wt_h,
    const _Float16* __restrict__ wt_l, const float* __restrict__ bV,
    const float* __restrict__ bU, const float* __restrict__ watt,
    float* __restrict__ raw) {
  __shared__ __align__(16) char smem[81920];
  _Float16* Ah = reinterpret_cast<_Float16*>(smem);            // 8 KB
  _Float16* Al = reinterpret_cast<_Float16*>(smem + 8192);     // 8 KB
  _Float16* Bh = reinterpret_cast<_Float16*>(smem + 16384);    // 32 KB
  _Float16* Bl = reinterpret_cast<_Float16*>(smem + 49152);    // 32 KB
  float* red = reinterpret_cast<float*>(smem);  // [128][5], aliases Ah/Al

  const int tid = threadIdx.x;
  const int lane = tid & 63;
  const int lc = lane & 15;
  const int lg = lane >> 4;
  const int w = __builtin_amdgcn_readfirstlane(tid >> 6);
  const int rg = w >> 2;  // 0..1
  const int cg = w & 3;   // 0..3
  const int row0 = blockIdx.x * 128;

  // staging thread mapping (step-invariant)
  const int rA = tid >> 2;
  const int gA = tid & 3;
  const float* aG = feat + (size_t)(row0 + rA) * D + gA * 8;
  const int aSlot = gA ^ SWZ(rA);
  const int nB0 = tid >> 2;
  const int gB = tid & 3;
  const int bSlot = gB ^ SWZ(nB0);
  const _Float16* bhG = wt_h + (size_t)nB0 * 512 + gB * 8;
  const _Float16* blG = wt_l + (size_t)nB0 * 512 + gB * 8;

  // frag read offsets (step-invariant, fp16 elems)
  int aoff[4], boff[8];
#pragma unroll
  for (int mt = 0; mt < 4; ++mt) {
    const int r = rg * 64 + mt * 16 + lc;
    aoff[mt] = r * 32 + ((lg ^ SWZ(r)) << 3);
  }
#pragma unroll
  for (int nt = 0; nt < 8; ++nt) {
    const int nbase = (nt < 4) ? cg * 64 + nt * 16 : 256 + cg * 64 + (nt - 4) * 16;
    const int n = nbase + lc;
    boff[nt] = n * 32 + ((lg ^ SWZ(n)) << 3);
  }

  f32x4 acc[4][8] = {};

  f32x4 a0, a1;
  i32x4 bhR0, bhR1, bhR2, bhR3, blR0, blR1, blR2, blR3;

  a0 = *(const f32x4*)(aG);
  a1 = *(const f32x4*)(aG + 4);
  bhR0 = *(const i32x4*)(bhG);
  bhR1 = *(const i32x4*)(bhG + 65536);
  bhR2 = *(const i32x4*)(bhG + 131072);
  bhR3 = *(const i32x4*)(bhG + 196608);
  blR0 = *(const i32x4*)(blG);
  blR1 = *(const i32x4*)(blG + 65536);
  blR2 = *(const i32x4*)(blG + 131072);
  blR3 = *(const i32x4*)(blG + 196608);

#pragma unroll 1
  for (int kt = 0; kt < 16; ++kt) {
    __syncthreads();  // (a) previous step's frag reads complete
    {
      f16x8 ahw, alw;
#pragma unroll
      for (int e = 0; e < 8; ++e) {
        const float x = (e < 4) ? a0[e] : a1[e - 4];
        const _Float16 h = (_Float16)x;
        ahw[e] = h;
        alw[e] = (_Float16)(x - (float)h);
      }
      const int aw = rA * 32 + (aSlot << 3);
      *(f16x8*)&Ah[aw] = ahw;
      *(f16x8*)&Al[aw] = alw;
      const int bw = nB0 * 32 + (bSlot << 3);
      *(i32x4*)&Bh[bw] = bhR0;
      *(i32x4*)&Bh[bw + 128 * 32] = bhR1;
      *(i32x4*)&Bh[bw + 256 * 32] = bhR2;
      *(i32x4*)&Bh[bw + 384 * 32] = bhR3;
      *(i32x4*)&Bl[bw] = blR0;
      *(i32x4*)&Bl[bw + 128 * 32] = blR1;
      *(i32x4*)&Bl[bw + 256 * 32] = blR2;
      *(i32x4*)&Bl[bw + 384 * 32] = blR3;
    }
    __syncthreads();  // (b) buffer ready
    if (kt < 15) {
      const int k0 = (kt + 1) * 32;
      a0 = *(const f32x4*)(aG + k0);
      a1 = *(const f32x4*)(aG + k0 + 4);
      bhR0 = *(const i32x4*)(bhG + k0);
      bhR1 = *(const i32x4*)(bhG + 65536 + k0);
      bhR2 = *(const i32x4*)(bhG + 131072 + k0);
      bhR3 = *(const i32x4*)(bhG + 196608 + k0);
      blR0 = *(const i32x4*)(blG + k0);
      blR1 = *(const i32x4*)(blG + 65536 + k0);
      blR2 = *(const i32x4*)(blG + 131072 + k0);
      blR3 = *(const i32x4*)(blG + 196608 + k0);
    }
    f16x8 ah[4], al[4];
#pragma unroll
    for (int mt = 0; mt < 4; ++mt) {
      ah[mt] = *(const f16x8*)&Ah[aoff[mt]];
      al[mt] = *(const f16x8*)&Al[aoff[mt]];
    }
#pragma unroll
    for (int nt = 0; nt < 8; ++nt) {
      const f16x8 bh = *(const f16x8*)&Bh[boff[nt]];
      const f16x8 bl = *(const f16x8*)&Bl[boff[nt]];
#pragma unroll
      for (int mt = 0; mt < 4; ++mt) {
        acc[mt][nt] =
            __builtin_amdgcn_mfma_f32_16x16x32_f16(ah[mt], bh, acc[mt][nt], 0, 0, 0);
        acc[mt][nt] =
            __builtin_amdgcn_mfma_f32_16x16x32_f16(ah[mt], bl, acc[mt][nt], 0, 0, 0);
        acc[mt][nt] =
            __builtin_amdgcn_mfma_f32_16x16x32_f16(al[mt], bh, acc[mt][nt], 0, 0, 0);
      }
    }
  }

  __syncthreads();  // all LDS frag reads done before red aliases the A-tile

  // epilogue: gate + reduce over this wave's 64 j-columns
#pragma unroll
  for (int mt = 0; mt < 4; ++mt) {
    float rs[4] = {0.f, 0.f, 0.f, 0.f};
#pragma unroll
    for (int nt = 0; nt < 4; ++nt) {
      const int j = cg * 64 + nt * 16 + lc;
      const float bv = bV[j], bu = bU[j], wa = watt[j];
#pragma unroll
      for (int rr = 0; rr < 4; ++rr) {
        const float cV = acc[mt][nt][rr] + bv;
        const float cU = acc[mt][nt + 4][rr] + bu;
        const float e2 = __expf(2.0f * cV);
        const float aV = 1.0f - 2.0f / (e2 + 1.0f);    // tanh
        const float aU = 1.0f / (1.0f + __expf(-cU));  // sigmoid
        rs[rr] += aV * aU * wa;
      }
    }
#pragma unroll
    for (int rr = 0; rr < 4; ++rr) {
      float v = rs[rr];
      v += __shfl_xor(v, 1, 16);
      v += __shfl_xor(v, 2, 16);
      v += __shfl_xor(v, 4, 16);
      v += __shfl_xor(v, 8, 16);
      if (lc == 0) red[(rg * 64 + mt * 16 + lg * 4 + rr) * 5 + cg] = v;
    }
  }
  __syncthreads();
  if (tid < 128)
    raw[row0 + tid] = red[tid * 5 + 0] + red[tid * 5 + 1] + red[tid * 5 + 2] +
                      red[tid * 5 + 3];
}

// ---- exclusive scan over 1024 per-thread counts --------------------------
__device__ __forceinline__ int scan1024(int c, int* wred, int tid) {
  const int lane = tid & 63, w = tid >> 6;
  int v = c;
#pragma unroll
  for (int off = 1; off < 64; off <<= 1) {
    const int u = __shfl_up(v, off, 64);
    if (lane >= off) v += u;
  }
  if (lane == 63) wred[w] = v;
  __syncthreads();
  if (tid == 0) {
    int run = 0;
    for (int i = 0; i < 16; ++i) {
      const int a = wred[i];
      wred[i] = run;
      run += a;
    }
  }
  __syncthreads();
  const int res = wred[w] + v - c;
  __syncthreads();
  return res;
}

// ---- K3: fused softmax + top-k threshold + membership + compaction -------
__global__ __launch_bounds__(1024) void select_kernel(
    const float* __restrict__ raw, const int* __restrict__ psel,
    float* __restrict__ attn_out, int* __restrict__ sel_ws,
    float* __restrict__ out_selidx) {
  const int b = blockIdx.x, t = threadIdx.x;
  const int lane = t & 63, w = t >> 6;
  __shared__ float sraw[N];        // 64 KB
  __shared__ int whist[16][256];   // 16 KB
  __shared__ int ghist[256];
  __shared__ float fred[16];
  __shared__ int wred[16];
  __shared__ float shM, shS;
  __shared__ uint32_t sh_prefix;
  __shared__ int sh_rk;
  const float* r = raw + b * N;

  // 1. load + max
  float m = -3.0e38f;
  for (int i = 0; i < 16; ++i) {
    const int idx = t + i * 1024;
    const float v = r[idx];
    sraw[idx] = v;
    m = fmaxf(m, v);
  }
  for (int off = 32; off > 0; off >>= 1) m = fmaxf(m, __shfl_down(m, off, 64));
  if (lane == 0) fred[w] = m;
  __syncthreads();
  if (t == 0) {
    float mm = fred[0];
    for (int i = 1; i < 16; ++i) mm = fmaxf(mm, fred[i]);
    shM = mm;
  }
  __syncthreads();
  const float M = shM;

  // 2. sum exp (keep the 16 exps in registers for step 3)
  float ex[16];
  float s = 0.f;
  for (int i = 0; i < 16; ++i) {
    ex[i] = expf(sraw[t + i * 1024] - M);
    s += ex[i];
  }
  for (int off = 32; off > 0; off >>= 1) s += __shfl_down(s, off, 64);
  if (lane == 0) fred[w] = s;
  __syncthreads();
  if (t == 0) {
    float ss = 0.f;
    for (int i = 0; i < 16; ++i) ss += fred[i];
    shS = ss;
  }
  __syncthreads();
  const float inv = 1.0f / shS;

  // 3. attn write
  for (int i = 0; i < 16; ++i)
    attn_out[b * N + t + i * 1024] = ex[i] * inv;

  // 4. radix select: threshold key + stable tie count
  uint32_t prefix = 0;
  int rk = N_TOP;
  for (int pass = 3; pass >= 0; --pass) {
    const int sh = pass * 8;
#pragma unroll
    for (int q = 0; q < 4; ++q) whist[w][lane * 4 + q] = 0;
    __syncthreads();
    for (int i = 0; i < 16; ++i) {
      const uint32_t key = f2key(sraw[t + i * 1024]);
      if (pass == 3 || (key >> (sh + 8)) == (prefix >> (sh + 8)))
        atomicAdd(&whist[w][(key >> sh) & 255], 1);
    }
    __syncthreads();
    if (t < 256) {
      int tot = 0;
      for (int ww = 0; ww < 16; ++ww) tot += whist[ww][t];
      ghist[t] = tot;
    }
    __syncthreads();
    // parallel descending digit search (suffix-inclusive scan, unique cross)
    int vS = 0, hrev = 0;
    if (t < 256) {
      hrev = ghist[255 - t];
      vS = hrev;
#pragma unroll
      for (int off = 1; off < 64; off <<= 1) {
        const int u2 = __shfl_up(vS, off, 64);
        if (lane >= off) vS += u2;
      }
      if (lane == 63) wred[t >> 6] = vS;
    }
    __syncthreads();
    if (t < 256) {
      int add = 0;
      const int w4 = t >> 6;
      for (int i = 0; i < w4; ++i) add += wred[i];
      const int incl = vS + add, excl = incl - hrev;
      if (incl >= rk && excl < rk) {
        sh_prefix = prefix | ((uint32_t)(255 - t) << sh);
        sh_rk = rk - excl;
      }
    }
    __syncthreads();
    prefix = sh_prefix;
    rk = sh_rk;
    __syncthreads();
  }
  const uint32_t T = prefix;
  const int tieTake = rk;

  // 5. membership + p-rank + psel lookup + selection (contiguous chunks)
  const int n0 = t * 16;
  int cgt = 0, ceq = 0;
  for (int i = 0; i < 16; ++i) {
    const uint32_t key = f2key(sraw[n0 + i]);
    cgt += (key > T);
    ceq += (key == T);
  }
  const int gbase = scan1024(cgt, wred, t);
  const int ebase = scan1024(ceq, wred, t);
  int grun = gbase, erun = ebase;
  unsigned selmask = 0;
  int csel = 0;
  for (int i = 0; i < 16; ++i) {
    const int n = n0 + i;
    const uint32_t key = f2key(sraw[n]);
    const bool gt = key > T, eq = key == T;
    const bool mem = gt || (eq && erun < tieTake);
    int sel;
    if (mem) {
      sel = 1;
    } else {
      const int members_before = grun + (erun < tieTake ? erun : tieTake);
      const int p = n - members_before;
      sel = psel[b * N_REM + p];
    }
    selmask |= (unsigned)sel << i;
    csel += sel;
    grun += gt;
    erun += eq;
  }
  int q = scan1024(csel, wred, t);
  for (int i = 0; i < 16; ++i) {
    if ((selmask >> i) & 1) {
      const int n = n0 + i;
      sel_ws[b * K_SEL + q] = n;
      out_selidx[b * K_SEL + q] = (float)n;
      ++q;
    }
  }
}

// ---- K4: gather selected feature rows ------------------------------------
__global__ __launch_bounds__(128) void gather_kernel(
    const float* __restrict__ feat, const int* __restrict__ sel_ws,
    float* __restrict__ out_sel) {
  const int qa = blockIdx.x;
  const int b = qa / K_SEL;
  const int n = sel_ws[qa];
  const float4* src =
      reinterpret_cast<const float4*>(feat + (size_t)(b * N + n) * D);
  float4* dst = reinterpret_cast<float4*>(out_sel + (size_t)qa * D);
  dst[threadIdx.x] = src[threadIdx.x];
}

extern "C" void kernel_launch(void* const* d_in, const int* in_sizes, int n_in,
                              void* d_out, int out_size, void* d_ws,
                              size_t ws_size, hipStream_t stream) {
  const float* feat = (const float*)d_in[0];
  const float* WV = (const float*)d_in[1];
  const float* bV = (const float*)d_in[2];
  const float* WU = (const float*)d_in[3];
  const float* bU = (const float*)d_in[4];
  const float* watt = (const float*)d_in[5];
  const float* batt = (const float*)d_in[6];
  (void)batt;  // softmax is shift-invariant; b_att cancels in all outputs

  float* out = (float*)d_out;
  float* out_selected = out;                      // B*K_SEL*D floats
  float* out_attn = out + (size_t)B * K_SEL * D;  // B*N floats
  float* out_selidx = out_attn + (size_t)B * N;   // B*K_SEL floats

  _Float16* wt_h = (_Float16*)d_ws;            // 512*512 fp16 = 512 KB
  _Float16* wt_l = wt_h + 512 * 512;           // 512 KB
  float* raw = (float*)(wt_l + 512 * 512);     // NROWS floats
  int* psel = (int*)(raw + NROWS);             // B*N_REM
  int* sel_ws = psel + B * N_REM;              // B*K_SEL

  prep_kernel<<<68, 256, 0, stream>>>(WV, WU, wt_h, wt_l, psel);
  score_kernel<<<NROWS / 128, 512, 0, stream>>>(feat, wt_h, wt_l, bV, bU, watt,
                                                raw);
  select_kernel<<<B, 1024, 0, stream>>>(raw, psel, out_attn, sel_ws,
                                        out_selidx);
  gather_kernel<<<B * K_SEL, 128, 0, stream>>>(feat, sel_ws, out_selected);
}

// Round 4
// 351.263 us; speedup vs baseline: 2.1388x; 1.0574x over previous
//
#include <hip/hip_runtime.h>
#include <stdint.h>

#define B 4
#define N 16384
#define D 512
#define H 256
#define NROWS (B * N)
#define K_SEL 11468
#define N_TOP 10322
#define N_RAND 1146
#define N_REM (N - N_TOP) /* 6062 */
#define HALF_CNT ((B * N_REM) / 2) /* 12124 */

typedef float f32x4 __attribute__((ext_vector_type(4)));
typedef _Float16 f16x8 __attribute__((ext_vector_type(8)));
typedef int i32x4 __attribute__((ext_vector_type(4)));

// async global->LDS 16B copy: LDS dest = wave-uniform base + lane*16
#define GLDS16(g, l)                                                    \
  __builtin_amdgcn_global_load_lds(                                     \
      (const __attribute__((address_space(1))) void*)(const void*)(g),  \
      (__attribute__((address_space(3))) void*)(void*)(l), 16, 0, 0)

// Monotone float -> uint key (larger float => larger key). No NaNs expected.
__device__ __forceinline__ uint32_t f2key(float x) {
  uint32_t u = __float_as_uint(x);
  return u ^ ((u & 0x80000000u) ? 0xFFFFFFFFu : 0x80000000u);
}

// ---- Threefry (matches jax.random.uniform(key(42)) stream) ---------------
__device__ __forceinline__ void threefry(uint32_t x0, uint32_t x1,
                                         uint32_t& o0, uint32_t& o1) {
  const uint32_t k0 = 0u, k1 = 42u;
  const uint32_t ks[3] = {k0, k1, k0 ^ k1 ^ 0x1BD11BDAu};
  x0 += ks[0];
  x1 += ks[1];
  const int R0[4] = {13, 15, 26, 6}, R1[4] = {17, 29, 16, 24};
#pragma unroll
  for (int i = 0; i < 5; ++i) {
    const int* R = (i & 1) ? R1 : R0;
#pragma unroll
    for (int jr = 0; jr < 4; ++jr) {
      x0 += x1;
      x1 = (x1 << R[jr]) | (x1 >> (32 - R[jr]));
      x1 ^= x0;
    }
    x0 += ks[(i + 1) % 3];
    x1 += ks[(i + 2) % 3] + (uint32_t)(i + 1);
  }
  o0 = x0;
  o1 = x1;
}

// ---- rand body: pick N_RAND smallest threefry scores -> psel bitmap ------
__device__ __forceinline__ void rand_body(const int b, int* __restrict__ psel,
                                          char* smem, const int t) {
  uint32_t* skey = reinterpret_cast<uint32_t*>(smem);           // N_REM*4
  uint32_t* hist = reinterpret_cast<uint32_t*>(smem + 24248);   // 256*4
  int* wr4 = reinterpret_cast<int*>(smem + 25272);              // 4*4
  uint32_t* shp = reinterpret_cast<uint32_t*>(smem + 25288);
  int* shrk = reinterpret_cast<int*>(smem + 25292);
  const int lane = t & 63, w4 = t >> 6;  // 4 waves

  for (int p = t; p < N_REM; p += 256) {
    psel[b * N_REM + p] = 0;
    const int f = b * N_REM + p;
    uint32_t o0, o1, bits;
    if (f < HALF_CNT) {
      threefry((uint32_t)f, (uint32_t)(f + HALF_CNT), o0, o1);
      bits = o0;
    } else {
      threefry((uint32_t)(f - HALF_CNT), (uint32_t)f, o0, o1);
      bits = o1;
    }
    const float u = __uint_as_float((bits >> 9) | 0x3f800000u) - 1.0f;
    skey[p] = f2key(u);
  }
  __syncthreads();

  uint32_t prefix = 0;
  int rk = N_RAND;
  for (int pass = 3; pass >= 0; --pass) {
    const int sh = pass * 8;
    hist[t] = 0;
    __syncthreads();
    for (int p = t; p < N_REM; p += 256) {
      const uint32_t key = skey[p];
      if (pass == 3 || (key >> (sh + 8)) == (prefix >> (sh + 8)))
        atomicAdd(&hist[(key >> sh) & 255], 1u);
    }
    __syncthreads();
    const int h = (int)hist[t];
    int v = h;
#pragma unroll
    for (int off = 1; off < 64; off <<= 1) {
      const int u2 = __shfl_up(v, off, 64);
      if (lane >= off) v += u2;
    }
    if (lane == 63) wr4[w4] = v;
    __syncthreads();
    int add = 0;
    for (int i = 0; i < w4; ++i) add += wr4[i];
    const int incl = v + add, excl = incl - h;
    if (incl >= rk && excl < rk) {
      *shp = prefix | ((uint32_t)t << sh);
      *shrk = rk - excl;
    }
    __syncthreads();
    prefix = *shp;
    rk = *shrk;
    __syncthreads();
  }

  const int CH = 24;  // 256*24 >= 6062
  const int p0 = t * CH;
  const int pe = (p0 + CH < N_REM) ? p0 + CH : N_REM;
  int ce = 0;
  for (int p = p0; p < pe; ++p) ce += (skey[p] == prefix);
  int v = ce;
#pragma unroll
  for (int off = 1; off < 64; off <<= 1) {
    const int u2 = __shfl_up(v, off, 64);
    if (lane >= off) v += u2;
  }
  if (lane == 63) wr4[w4] = v;
  __syncthreads();
  if (t == 0) {
    int run = 0;
    for (int i = 0; i < 4; ++i) {
      const int a = wr4[i];
      wr4[i] = run;
      run += a;
    }
  }
  __syncthreads();
  int ge = wr4[w4] + v - ce;
  for (int p = p0; p < pe; ++p) {
    const uint32_t key = skey[p];
    const bool pick = (key < prefix) || (key == prefix && ge < rk);
    ge += (key == prefix);
    if (pick) psel[b * N_REM + p] = 1;
  }
}

// ---- K0: fused prep. Blocks 0-63: W^T fp16 hi/lo, written STEP-CHUNKED:
// wt[s*16384 + n*32 + kl] = W^T[n][s*32+kl]  (s = k-step 0..15, n 0..511).
// Linear copy of one 32KB chunk into LDS is then exactly the frag layout.
// Blocks 64-67: rand selection (independent, overlapped).
__global__ __launch_bounds__(256) void prep_kernel(
    const float* __restrict__ WV, const float* __restrict__ WU,
    _Float16* __restrict__ wt_h, _Float16* __restrict__ wt_l,
    int* __restrict__ psel) {
  __shared__ __align__(16) char pmem[25296];
  if (blockIdx.x >= 64) {
    rand_body(blockIdx.x - 64, psel, pmem, threadIdx.x);
    return;
  }
  _Float16(*th)[65] = reinterpret_cast<_Float16(*)[65]>(pmem);
  _Float16(*tl)[65] = reinterpret_cast<_Float16(*)[65]>(pmem + 8320);
  const int kb = (blockIdx.x >> 3) * 64;
  const int nb = (blockIdx.x & 7) * 64;
  const int tx = threadIdx.x & 63;
  const int ty = threadIdx.x >> 6;
  const float* src = (nb < 256) ? WV : WU;
  const int nsrc = nb & 255;
#pragma unroll
  for (int i = 0; i < 16; ++i) {
    const int k = ty + i * 4;
    const float x = src[(size_t)(kb + k) * H + nsrc + tx];
    const _Float16 h = (_Float16)x;
    th[k][tx] = h;
    tl[k][tx] = (_Float16)(x - (float)h);
  }
  __syncthreads();
  const int n_local = threadIdx.x & 63;
  const int c2 = threadIdx.x >> 6;
  const int s_local = c2 >> 1, half = c2 & 1;
  const int n = nb + n_local;
  const int s = (kb >> 5) + s_local;
  const int klb = s_local * 32 + half * 16;
  f16x8 vh0, vh1, vl0, vl1;
#pragma unroll
  for (int e = 0; e < 8; ++e) {
    vh0[e] = th[klb + e][n_local];
    vh1[e] = th[klb + 8 + e][n_local];
    vl0[e] = tl[klb + e][n_local];
    vl1[e] = tl[klb + 8 + e][n_local];
  }
  const size_t o = (size_t)s * 16384 + (size_t)n * 32 + half * 16;
  *reinterpret_cast<f16x8*>(wt_h + o) = vh0;
  *reinterpret_cast<f16x8*>(wt_h + o + 8) = vh1;
  *reinterpret_cast<f16x8*>(wt_l + o) = vl0;
  *reinterpret_cast<f16x8*>(wt_l + o + 8) = vl1;
}

// ---- K1: fused gated-attention raw scores via MFMA (fp16 hi/lo split).
// 512 wg x 512 thr. BM=128, BN=512, K-step 32, 16 steps.
// Pipelined: B tiles double-buffered via async global_load_lds (issued at
// iter top, drained by the post-compute barrier ~1000cyc later); A issued
// at iter top into regs (sched_barrier pins issue before the MFMA block),
// converted to fp16 hi/lo and written to LDS after bar1 (T14 split).
// Linear LDS layouts (64B rows) are bank-balanced for both write and frag
// read patterns; no swizzle. Math/order bit-identical to the R2 kernel.
__global__ __launch_bounds__(512) void score_kernel(
    const float* __restrict__ feat, const _Float16* __restrict__ wt_h,
    const _Float16* __restrict__ wt_l, const float* __restrict__ bV,
    const float* __restrict__ bU, const float* __restrict__ watt,
    float* __restrict__ raw) {
  __shared__ _Float16 Ah[128 * 32];    // 8 KB
  __shared__ _Float16 Al[128 * 32];    // 8 KB
  __shared__ _Float16 Bh0[512 * 32];   // 32 KB
  __shared__ _Float16 Bl0[512 * 32];   // 32 KB
  __shared__ _Float16 Bh1[512 * 32];   // 32 KB
  __shared__ _Float16 Bl1[512 * 32];   // 32 KB
  __shared__ float red[128][5];        // 2.5 KB

  const int tid = threadIdx.x;
  const int lane = tid & 63;
  const int lc = lane & 15;
  const int lg = lane >> 4;
  const int w = __builtin_amdgcn_readfirstlane(tid >> 6);
  const int rg = w >> 2;  // 0..1
  const int cg = w & 3;   // 0..3
  const int row0 = blockIdx.x * 128;

  // A staging: thread covers row rA, granule gA (8 floats)
  const int rA = tid >> 2;
  const int gA = tid & 3;
  const float* aG = feat + (size_t)(row0 + rA) * D + gA * 8;
  const int awOff = rA * 32 + gA * 8;  // f16 idx, linear

  // B staging via global_load_lds: wave w covers f16 range [w*2048, +2048)
  // of each 16384-elem step chunk, in 4 issues of 512 f16 (1 KB) per half.
  const _Float16* pbh = wt_h + (size_t)w * 2048 + lane * 8;
  const _Float16* pbl = wt_l + (size_t)w * 2048 + lane * 8;
  const int ldsB = w * 2048;  // f16 idx

  // frag read offsets (step-invariant, f16 elems)
  int aoff[4], boff[8];
#pragma unroll
  for (int mt = 0; mt < 4; ++mt)
    aoff[mt] = (rg * 64 + mt * 16 + lc) * 32 + lg * 8;
#pragma unroll
  for (int nt = 0; nt < 8; ++nt) {
    const int nbase =
        (nt < 4) ? cg * 64 + nt * 16 : 256 + cg * 64 + (nt - 4) * 16;
    boff[nt] = (nbase + lc) * 32 + lg * 8;
  }

  f32x4 acc[4][8] = {};
  f32x4 a0, a1;

  // ---- prologue: stage step 0 ----
  a0 = *(const f32x4*)(aG);
  a1 = *(const f32x4*)(aG + 4);
#pragma unroll
  for (int i = 0; i < 4; ++i) {
    GLDS16(pbh + i * 512, &Bh0[ldsB + i * 512]);
    GLDS16(pbl + i * 512, &Bl0[ldsB + i * 512]);
  }
  {
    f16x8 ahw, alw;
#pragma unroll
    for (int e = 0; e < 8; ++e) {
      const float x = (e < 4) ? a0[e] : a1[e - 4];
      const _Float16 h = (_Float16)x;
      ahw[e] = h;
      alw[e] = (_Float16)(x - (float)h);
    }
    *(f16x8*)&Ah[awOff] = ahw;
    *(f16x8*)&Al[awOff] = alw;
  }
  __syncthreads();

#pragma unroll 1
  for (int kt = 0; kt < 16; ++kt) {
    const int knx = (kt + 1) & 15;  // wrap: last iter restages step 0 (unused)
    _Float16* BhN = (kt & 1) ? Bh0 : Bh1;
    _Float16* BlN = (kt & 1) ? Bl0 : Bl1;
    const _Float16* BhC = (kt & 1) ? Bh1 : Bh0;
    const _Float16* BlC = (kt & 1) ? Bl1 : Bl0;

    // issue next-step B (async -> LDS buf^1) and A (-> regs) EARLY
#pragma unroll
    for (int i = 0; i < 4; ++i) {
      GLDS16(pbh + knx * 16384 + i * 512, &BhN[ldsB + i * 512]);
      GLDS16(pbl + knx * 16384 + i * 512, &BlN[ldsB + i * 512]);
    }
    a0 = *(const f32x4*)(aG + knx * 32);
    a1 = *(const f32x4*)(aG + knx * 32 + 4);
    __builtin_amdgcn_sched_barrier(0);  // pin load issue before compute

    // ---- compute step kt ----
    f16x8 ah[4], al[4];
#pragma unroll
    for (int mt = 0; mt < 4; ++mt) {
      ah[mt] = *(const f16x8*)&Ah[aoff[mt]];
      al[mt] = *(const f16x8*)&Al[aoff[mt]];
    }
#pragma unroll
    for (int nt = 0; nt < 8; ++nt) {
      const f16x8 bh = *(const f16x8*)&BhC[boff[nt]];
      const f16x8 bl = *(const f16x8*)&BlC[boff[nt]];
#pragma unroll
      for (int mt = 0; mt < 4; ++mt) {
        acc[mt][nt] = __builtin_amdgcn_mfma_f32_16x16x32_f16(ah[mt], bh,
                                                             acc[mt][nt], 0, 0, 0);
        acc[mt][nt] = __builtin_amdgcn_mfma_f32_16x16x32_f16(ah[mt], bl,
                                                             acc[mt][nt], 0, 0, 0);
        acc[mt][nt] = __builtin_amdgcn_mfma_f32_16x16x32_f16(al[mt], bh,
                                                             acc[mt][nt], 0, 0, 0);
      }
    }
    __syncthreads();  // bar1: A-tile reads done; drains B(knx) + a0/a1

    // write A(knx) into the single A buffer
    {
      f16x8 ahw, alw;
#pragma unroll
      for (int e = 0; e < 8; ++e) {
        const float x = (e < 4) ? a0[e] : a1[e - 4];
        const _Float16 h = (_Float16)x;
        ahw[e] = h;
        alw[e] = (_Float16)(x - (float)h);
      }
      *(f16x8*)&Ah[awOff] = ahw;
      *(f16x8*)&Al[awOff] = alw;
    }
    __syncthreads();  // bar2: A(knx) visible
  }

  // ---- epilogue: gate + reduce over this wave's 64 j-columns ----
#pragma unroll
  for (int mt = 0; mt < 4; ++mt) {
    float rs[4] = {0.f, 0.f, 0.f, 0.f};
#pragma unroll
    for (int nt = 0; nt < 4; ++nt) {
      const int j = cg * 64 + nt * 16 + lc;
      const float bv = bV[j], bu = bU[j], wa = watt[j];
#pragma unroll
      for (int rr = 0; rr < 4; ++rr) {
        const float cV = acc[mt][nt][rr] + bv;
        const float cU = acc[mt][nt + 4][rr] + bu;
        const float e2 = __expf(2.0f * cV);
        const float aV = 1.0f - 2.0f / (e2 + 1.0f);    // tanh
        const float aU = 1.0f / (1.0f + __expf(-cU));  // sigmoid
        rs[rr] += aV * aU * wa;
      }
    }
#pragma unroll
    for (int rr = 0; rr < 4; ++rr) {
      float v = rs[rr];
      v += __shfl_xor(v, 1, 16);
      v += __shfl_xor(v, 2, 16);
      v += __shfl_xor(v, 4, 16);
      v += __shfl_xor(v, 8, 16);
      if (lc == 0) red[rg * 64 + mt * 16 + lg * 4 + rr][cg] = v;
    }
  }
  __syncthreads();
  if (tid < 128)
    raw[row0 + tid] = red[tid][0] + red[tid][1] + red[tid][2] + red[tid][3];
}

// ---- exclusive scan over 1024 per-thread counts --------------------------
__device__ __forceinline__ int scan1024(int c, int* wred, int tid) {
  const int lane = tid & 63, w = tid >> 6;
  int v = c;
#pragma unroll
  for (int off = 1; off < 64; off <<= 1) {
    const int u = __shfl_up(v, off, 64);
    if (lane >= off) v += u;
  }
  if (lane == 63) wred[w] = v;
  __syncthreads();
  if (tid == 0) {
    int run = 0;
    for (int i = 0; i < 16; ++i) {
      const int a = wred[i];
      wred[i] = run;
      run += a;
    }
  }
  __syncthreads();
  const int res = wred[w] + v - c;
  __syncthreads();
  return res;
}

// ---- K3: fused softmax + top-k threshold + membership + compaction -------
__global__ __launch_bounds__(1024) void select_kernel(
    const float* __restrict__ raw, const int* __restrict__ psel,
    float* __restrict__ attn_out, int* __restrict__ sel_ws,
    float* __restrict__ out_selidx) {
  const int b = blockIdx.x, t = threadIdx.x;
  const int lane = t & 63, w = t >> 6;
  __shared__ float sraw[N];        // 64 KB
  __shared__ int whist[16][256];   // 16 KB
  __shared__ int ghist[256];
  __shared__ float fred[16];
  __shared__ int wred[16];
  __shared__ float shM, shS;
  __shared__ uint32_t sh_prefix;
  __shared__ int sh_rk;
  const float* r = raw + b * N;

  // 1. load + max
  float m = -3.0e38f;
  for (int i = 0; i < 16; ++i) {
    const int idx = t + i * 1024;
    const float v = r[idx];
    sraw[idx] = v;
    m = fmaxf(m, v);
  }
  for (int off = 32; off > 0; off >>= 1) m = fmaxf(m, __shfl_down(m, off, 64));
  if (lane == 0) fred[w] = m;
  __syncthreads();
  if (t == 0) {
    float mm = fred[0];
    for (int i = 1; i < 16; ++i) mm = fmaxf(mm, fred[i]);
    shM = mm;
  }
  __syncthreads();
  const float M = shM;

  // 2. sum exp (keep the 16 exps in registers for step 3)
  float ex[16];
  float s = 0.f;
  for (int i = 0; i < 16; ++i) {
    ex[i] = expf(sraw[t + i * 1024] - M);
    s += ex[i];
  }
  for (int off = 32; off > 0; off >>= 1) s += __shfl_down(s, off, 64);
  if (lane == 0) fred[w] = s;
  __syncthreads();
  if (t == 0) {
    float ss = 0.f;
    for (int i = 0; i < 16; ++i) ss += fred[i];
    shS = ss;
  }
  __syncthreads();
  const float inv = 1.0f / shS;

  // 3. attn write
  for (int i = 0; i < 16; ++i)
    attn_out[b * N + t + i * 1024] = ex[i] * inv;

  // 4. radix select: threshold key + stable tie count
  uint32_t prefix = 0;
  int rk = N_TOP;
  for (int pass = 3; pass >= 0; --pass) {
    const int sh = pass * 8;
#pragma unroll
    for (int q = 0; q < 4; ++q) whist[w][lane * 4 + q] = 0;
    __syncthreads();
    for (int i = 0; i < 16; ++i) {
      const uint32_t key = f2key(sraw[t + i * 1024]);
      if (pass == 3 || (key >> (sh + 8)) == (prefix >> (sh + 8)))
        atomicAdd(&whist[w][(key >> sh) & 255], 1);
    }
    __syncthreads();
    if (t < 256) {
      int tot = 0;
      for (int ww = 0; ww < 16; ++ww) tot += whist[ww][t];
      ghist[t] = tot;
    }
    __syncthreads();
    int vS = 0, hrev = 0;
    if (t < 256) {
      hrev = ghist[255 - t];
      vS = hrev;
#pragma unroll
      for (int off = 1; off < 64; off <<= 1) {
        const int u2 = __shfl_up(vS, off, 64);
        if (lane >= off) vS += u2;
      }
      if (lane == 63) wred[t >> 6] = vS;
    }
    __syncthreads();
    if (t < 256) {
      int add = 0;
      const int w4 = t >> 6;
      for (int i = 0; i < w4; ++i) add += wred[i];
      const int incl = vS + add, excl = incl - hrev;
      if (incl >= rk && excl < rk) {
        sh_prefix = prefix | ((uint32_t)(255 - t) << sh);
        sh_rk = rk - excl;
      }
    }
    __syncthreads();
    prefix = sh_prefix;
    rk = sh_rk;
    __syncthreads();
  }
  const uint32_t T = prefix;
  const int tieTake = rk;

  // 5. membership + p-rank + psel lookup + selection (contiguous chunks)
  const int n0 = t * 16;
  int cgt = 0, ceq = 0;
  for (int i = 0; i < 16; ++i) {
    const uint32_t key = f2key(sraw[n0 + i]);
    cgt += (key > T);
    ceq += (key == T);
  }
  const int gbase = scan1024(cgt, wred, t);
  const int ebase = scan1024(ceq, wred, t);
  int grun = gbase, erun = ebase;
  unsigned selmask = 0;
  int csel = 0;
  for (int i = 0; i < 16; ++i) {
    const int n = n0 + i;
    const uint32_t key = f2key(sraw[n]);
    const bool gt = key > T, eq = key == T;
    const bool mem = gt || (eq && erun < tieTake);
    int sel;
    if (mem) {
      sel = 1;
    } else {
      const int members_before = grun + (erun < tieTake ? erun : tieTake);
      const int p = n - members_before;
      sel = psel[b * N_REM + p];
    }
    selmask |= (unsigned)sel << i;
    csel += sel;
    grun += gt;
    erun += eq;
  }
  int q = scan1024(csel, wred, t);
  for (int i = 0; i < 16; ++i) {
    if ((selmask >> i) & 1) {
      const int n = n0 + i;
      sel_ws[b * K_SEL + q] = n;
      out_selidx[b * K_SEL + q] = (float)n;
      ++q;
    }
  }
}

// ---- K4: gather selected feature rows ------------------------------------
__global__ __launch_bounds__(128) void gather_kernel(
    const float* __restrict__ feat, const int* __restrict__ sel_ws,
    float* __restrict__ out_sel) {
  const int qa = blockIdx.x;
  const int b = qa / K_SEL;
  const int n = sel_ws[qa];
  const float4* src =
      reinterpret_cast<const float4*>(feat + (size_t)(b * N + n) * D);
  float4* dst = reinterpret_cast<float4*>(out_sel + (size_t)qa * D);
  dst[threadIdx.x] = src[threadIdx.x];
}

extern "C" void kernel_launch(void* const* d_in, const int* in_sizes, int n_in,
                              void* d_out, int out_size, void* d_ws,
                              size_t ws_size, hipStream_t stream) {
  const float* feat = (const float*)d_in[0];
  const float* WV = (const float*)d_in[1];
  const float* bV = (const float*)d_in[2];
  const float* WU = (const float*)d_in[3];
  const float* bU = (const float*)d_in[4];
  const float* watt = (const float*)d_in[5];
  const float* batt = (const float*)d_in[6];
  (void)batt;  // softmax is shift-invariant; b_att cancels in all outputs

  float* out = (float*)d_out;
  float* out_selected = out;                      // B*K_SEL*D floats
  float* out_attn = out + (size_t)B * K_SEL * D;  // B*N floats
  float* out_selidx = out_attn + (size_t)B * N;   // B*K_SEL floats

  _Float16* wt_h = (_Float16*)d_ws;            // 512*512 fp16 = 512 KB
  _Float16* wt_l = wt_h + 512 * 512;           // 512 KB
  float* raw = (float*)(wt_l + 512 * 512);     // NROWS floats
  int* psel = (int*)(raw + NROWS);             // B*N_REM
  int* sel_ws = psel + B * N_REM;              // B*K_SEL

  prep_kernel<<<68, 256, 0, stream>>>(WV, WU, wt_h, wt_l, psel);
  score_kernel<<<NROWS / 128, 512, 0, stream>>>(feat, wt_h, wt_l, bV, bU, watt,
                                                raw);
  select_kernel<<<B, 1024, 0, stream>>>(raw, psel, out_attn, sel_ws,
                                        out_selidx);
  gather_kernel<<<B * K_SEL, 128, 0, stream>>>(feat, sel_ws, out_selected);
}